// Round 10
// baseline (255.674 us; speedup 1.0000x reference)
//
#include <hip/hip_runtime.h>

#define LOG2E 1.4426950408889634f
#define NB 4
#define NL 256
#define ND 256
#define NH 256

typedef __attribute__((ext_vector_type(8))) short s16x8;
typedef __attribute__((ext_vector_type(4))) short s16x4;
typedef __attribute__((ext_vector_type(4))) float f32x4;

static __device__ __forceinline__ float b2f(unsigned short u) {
  return __builtin_bit_cast(float, (unsigned int)u << 16);
}
static __device__ __forceinline__ unsigned short f2b(float f) {
  unsigned int x = __builtin_bit_cast(unsigned int, f);
  return (unsigned short)((x + 0x7fffu + ((x >> 16) & 1u)) >> 16);
}
static __device__ __forceinline__ float ftanh(float x) {
  float e = __builtin_amdgcn_exp2f(x * 2.8853900817779268f);
  return 1.0f - 2.0f * __builtin_amdgcn_rcpf(e + 1.0f);
}

// ws layout (4 MB, <= R9-proven 4.5 MB):
//   X    fp32 [0,    1M)  : Hq@Wb
//   C1   bf16 [1M, 1.5M)  : Hq@Wc1
//   M1   bf16 [1.5M, 2M)  : Hq@Wm
//   C2b  bf16 [2M, 2.5M)  : Hp@Wc2
//   M2b  bf16 [2.5M, 3M)  : Hp@Wm
//   Hqb  bf16 [3M, 3.5M)  : bf16(Hq)
//   WdTb bf16 [3.5M, 4M)  : bf16(Wd^T)  [h][k]
// Scores (c,b,d,m) live in d_out regions 0..3 between K2 and K3.

__global__ void __launch_bounds__(256) prep(
    const float* __restrict__ Hq, const float* __restrict__ Hp,
    const float* __restrict__ Wc1, const float* __restrict__ Wc2,
    const float* __restrict__ Wb, const float* __restrict__ Wm,
    const float* __restrict__ Wd, float* __restrict__ ws)
{
  const int which = blockIdx.y;  // 0=C1 1=M1 2=X 3=C2b 4=M2b 5=Hqb 6=WdTb
  const int tid = threadIdx.x;
  if (which == 6) { // LDS-tile transpose Wd[k][h] -> WdTb[h][k] bf16
    if (blockIdx.x >= 16) return;
    const int k0 = (blockIdx.x >> 2) * 64, h0 = (blockIdx.x & 3) * 64;
    __shared__ unsigned short tile[64][65];
    unsigned short* WdTb = (unsigned short*)((char*)ws + 3670016);
    #pragma unroll
    for (int i = 0; i < 16; ++i) {
      const int idx = i * 256 + tid;
      const int kk = idx >> 6, hh = idx & 63;
      tile[kk][hh] = f2b(Wd[(k0 + kk) * NH + h0 + hh]);
    }
    __syncthreads();
    #pragma unroll
    for (int i = 0; i < 16; ++i) {
      const int idx = i * 256 + tid;
      const int hh = idx >> 6, kk = idx & 63;
      WdTb[(h0 + hh) * ND + k0 + kk] = tile[kk][hh];
    }
    return;
  }
  const int m0 = blockIdx.x * 8;
  if (which == 5) {
    unsigned short* Hqb = (unsigned short*)((char*)ws + 3145728);
    #pragma unroll
    for (int j = 0; j < 8; ++j)
      Hqb[(m0 + j) * ND + tid] = f2b(Hq[(m0 + j) * ND + tid]);
    return;
  }
  __shared__ __align__(16) float a_s[8][256];
  const float* A = (which >= 3) ? Hp : Hq;
  const float* W = (which == 0) ? Wc1 : (which == 1) ? Wm :
                   (which == 2) ? Wb  : (which == 3) ? Wc2 : Wm;
  #pragma unroll
  for (int j = 0; j < 8; ++j)
    a_s[j][tid] = A[(m0 + j) * ND + tid];
  __syncthreads();
  float acc[8] = {0.f, 0.f, 0.f, 0.f, 0.f, 0.f, 0.f, 0.f};
  for (int k = 0; k < 256; ++k) {
    const float w = W[k * NH + tid];
    #pragma unroll
    for (int j = 0; j < 8; ++j) acc[j] += a_s[j][k] * w;
  }
  if (which == 2) {
    #pragma unroll
    for (int j = 0; j < 8; ++j) ws[(m0 + j) * NH + tid] = acc[j];
  } else {
    const int base = (which < 2) ? (1048576 + which * 524288)
                                 : (2097152 + (which - 3) * 524288);
    unsigned short* O = (unsigned short*)((char*)ws + base);
    #pragma unroll
    for (int j = 0; j < 8; ++j) O[(m0 + j) * NH + tid] = f2b(acc[j]);
  }
}

// ---- K2: 2048 blocks; even = branch-d MFMA block, odd = c/b/m score block.
__global__ void __launch_bounds__(256, 4) k2(
    const float* __restrict__ Hp, const float* __restrict__ vc,
    const float* __restrict__ vd, const float* __restrict__ vm,
    const float* __restrict__ ws, float* __restrict__ out)
{
  const int type = blockIdx.x & 1;
  const int id = (blockIdx.x >> 1);
  const int p = id & (NL - 1), b = id >> 8;
  const int tid = threadIdx.x;
  const int wave = tid >> 6, lane = tid & 63;
  const int quad = lane >> 4, c16 = lane & 15;

  __shared__ __align__(16) short Bs[64 * 264];  // d-path only
  __shared__ __align__(16) float hp_s[256];
  __shared__ __align__(16) float v1_s[256];     // d: vd | sc: vc
  __shared__ __align__(16) float v2_s[256];     // sc: vm
  __shared__ __align__(16) float c2_s[256];
  __shared__ __align__(16) float m2_s[256];

  const unsigned short* Hqb  = (const unsigned short*)((const char*)ws + 3145728);
  const unsigned short* WdTb = (const unsigned short*)((const char*)ws + 3670016);

  if (type == 0) {
    // ---------- branch d ----------
    hp_s[tid] = Hp[(b * NL + p) * ND + tid];
    v1_s[tid] = vd[tid];
    __syncthreads();

    const int wq0 = wave * 64;
    const unsigned short* Aq = Hqb + (b * NL + wq0) * ND;
    float sd_reg[4][4];
    #pragma unroll
    for (int mt = 0; mt < 4; ++mt)
      #pragma unroll
      for (int r = 0; r < 4; ++r) sd_reg[mt][r] = 0.f;

    for (int ht = 0; ht < 4; ++ht) {
      const int h0 = ht * 64;
      __syncthreads();
      { // stage Bs[h][k] = bf16(WdTb[h0+h][k] * hp[k]); thread: h=tid&63, k-quarter=tid>>6
        const int h = tid & 63, kq = tid >> 6;
        const unsigned short* src = WdTb + (h0 + h) * ND + kq * 64;
        short* dst = Bs + h * 264 + kq * 64;
        #pragma unroll
        for (int i = 0; i < 8; ++i) {
          s16x8 w8 = *(const s16x8*)(src + i * 8);
          s16x8 bv;
          #pragma unroll
          for (int j = 0; j < 8; ++j)
            bv[j] = (short)f2b(b2f((unsigned short)w8[j]) * hp_s[kq * 64 + i * 8 + j]);
          *(s16x8*)(dst + i * 8) = bv;
        }
      }
      __syncthreads();

      f32x4 acc[4][4];
      #pragma unroll
      for (int mt = 0; mt < 4; ++mt)
        #pragma unroll
        for (int nt = 0; nt < 4; ++nt) acc[mt][nt] = f32x4{0.f, 0.f, 0.f, 0.f};

      #pragma unroll 2
      for (int kt = 0; kt < 8; ++kt) {
        const int k0 = kt * 32;
        s16x8 a8[4];
        #pragma unroll
        for (int mt = 0; mt < 4; ++mt)
          a8[mt] = *(const s16x8*)(Aq + (mt * 16 + c16) * ND + k0 + quad * 8);
        #pragma unroll
        for (int nt = 0; nt < 4; ++nt) {
          s16x8 b8 = *(const s16x8*)(Bs + (nt * 16 + c16) * 264 + k0 + quad * 8);
          #pragma unroll
          for (int mt = 0; mt < 4; ++mt)
            acc[mt][nt] = __builtin_amdgcn_mfma_f32_16x16x32_bf16(
                a8[mt], b8, acc[mt][nt], 0, 0, 0);
        }
      }

      // sd[q] += sum_h vd[h]*tanh(Z[q,h]); C/D: col=lane&15, row=quad*4+r
      #pragma unroll
      for (int mt = 0; mt < 4; ++mt) {
        float part[4] = {0.f, 0.f, 0.f, 0.f};
        #pragma unroll
        for (int nt = 0; nt < 4; ++nt) {
          const float vdh = v1_s[h0 + nt * 16 + c16];
          #pragma unroll
          for (int r = 0; r < 4; ++r)
            part[r] += vdh * ftanh(acc[mt][nt][r]);
        }
        #pragma unroll
        for (int r = 0; r < 4; ++r) {
          float v = part[r];
          #pragma unroll
          for (int m = 1; m < 16; m <<= 1) v += __shfl_xor(v, m, 64);
          sd_reg[mt][r] += v;
        }
      }
    }
    if (c16 == 0) {
      float* SD = out + ((2 * NB + b) * NL + p) * ND;
      #pragma unroll
      for (int mt = 0; mt < 4; ++mt)
        #pragma unroll
        for (int r = 0; r < 4; ++r)
          SD[wq0 + mt * 16 + quad * 4 + r] = sd_reg[mt][r];
    }
  } else {
    // ---------- scores c, b, m ----------
    const float* X = ws;
    const unsigned short* C1  = (const unsigned short*)((const char*)ws + 1048576);
    const unsigned short* M1  = (const unsigned short*)((const char*)ws + 1572864);
    const unsigned short* C2b = (const unsigned short*)((const char*)ws + 2097152);
    const unsigned short* M2b = (const unsigned short*)((const char*)ws + 2621440);

    {
      const int r = (b * NL + p) * ND + tid;
      hp_s[tid] = Hp[r];
      c2_s[tid] = b2f(C2b[r]);
      m2_s[tid] = b2f(M2b[r]);
      v1_s[tid] = vc[tid];
      v2_s[tid] = vm[tid];
    }
    __syncthreads();

    const int qsub = lane >> 4;
    const int hb = c16 * 4;
    for (int qg = 0; qg < 16; ++qg) {
      const int q = wave * 64 + qg * 4 + qsub;
      const unsigned short* c1r = C1 + (b * NL + q) * NH;
      const unsigned short* m1r = M1 + (b * NL + q) * NH;
      const float* xr = X + (b * NL + q) * ND;
      float pc = 0.f, pm = 0.f, pb = 0.f;
      #pragma unroll
      for (int hi = 0; hi < 4; ++hi) {
        const int h = hb + hi * 64;
        s16x4 c1v = *(const s16x4*)(c1r + h);
        s16x4 m1v = *(const s16x4*)(m1r + h);
        f32x4 xv  = *(const f32x4*)(xr + h);
        #pragma unroll
        for (int i = 0; i < 4; ++i) {
          pc += v1_s[h + i] * ftanh(b2f((unsigned short)c1v[i]) + c2_s[h + i]);
          pm += v2_s[h + i] * ftanh(b2f((unsigned short)m1v[i]) - m2_s[h + i]);
          pb += hp_s[h + i] * xv[i];
        }
      }
      #pragma unroll
      for (int m = 1; m < 16; m <<= 1) {
        pc += __shfl_xor(pc, m, 64);
        pm += __shfl_xor(pm, m, 64);
        pb += __shfl_xor(pb, m, 64);
      }
      if (c16 == 0) {
        out[((0 * NB + b) * NL + p) * ND + q] = pc;
        out[((1 * NB + b) * NL + p) * ND + q] = pb;
        out[((3 * NB + b) * NL + p) * ND + q] = pm;
      }
    }
  }
}

// ---- K3: softmax (4 branches) + attend + final store (in-place over scores)
__global__ void __launch_bounds__(256) k3(
    const float* __restrict__ Hq, float* __restrict__ out)
{
  const int p = blockIdx.x, b = blockIdx.y;
  const int tid = threadIdx.x;
  const int wave = tid >> 6, lane = tid & 63;

  __shared__ __align__(16) float sc4[4 * 256];
  __shared__ __align__(16) float red[4][4][256];
  __shared__ __align__(16) float invsum[4];

  #pragma unroll
  for (int br = 0; br < 4; ++br)
    sc4[br * 256 + tid] = out[((br * NB + b) * NL + p) * ND + tid];
  __syncthreads();

  { // softmax; wave w owns branch w
    float s0 = sc4[wave * 256 + lane];
    float s1 = sc4[wave * 256 + lane + 64];
    float s2 = sc4[wave * 256 + lane + 128];
    float s3 = sc4[wave * 256 + lane + 192];
    float mx = fmaxf(fmaxf(s0, s1), fmaxf(s2, s3));
    #pragma unroll
    for (int m = 1; m < 64; m <<= 1) mx = fmaxf(mx, __shfl_xor(mx, m, 64));
    float e0 = __builtin_amdgcn_exp2f((s0 - mx) * LOG2E);
    float e1 = __builtin_amdgcn_exp2f((s1 - mx) * LOG2E);
    float e2 = __builtin_amdgcn_exp2f((s2 - mx) * LOG2E);
    float e3 = __builtin_amdgcn_exp2f((s3 - mx) * LOG2E);
    float sm = e0 + e1 + e2 + e3;
    #pragma unroll
    for (int m = 1; m < 64; m <<= 1) sm += __shfl_xor(sm, m, 64);
    sc4[wave * 256 + lane]       = e0;
    sc4[wave * 256 + lane + 64]  = e1;
    sc4[wave * 256 + lane + 128] = e2;
    sc4[wave * 256 + lane + 192] = e3;
    if (lane == 0) invsum[wave] = __builtin_amdgcn_rcpf(sm);
  }
  __syncthreads();

  { // attend: wave w covers q in [64w,64w+64) for ALL branches
    const int q0 = wave * 64;
    f32x4 pa0 = {0.f,0.f,0.f,0.f}, pa1 = {0.f,0.f,0.f,0.f};
    f32x4 pa2 = {0.f,0.f,0.f,0.f}, pa3 = {0.f,0.f,0.f,0.f};
    for (int qi = 0; qi < 64; ++qi) {
      const int q = q0 + qi;
      const float ac = sc4[q];
      const float ab = sc4[256 + q];
      const float ad = sc4[512 + q];
      const float am = sc4[768 + q];
      f32x4 hv = *(const f32x4*)(Hq + (b * NL + q) * ND + lane * 4);
      pa0 += ac * hv; pa1 += ab * hv; pa2 += ad * hv; pa3 += am * hv;
    }
    *(f32x4*)(&red[wave][0][lane * 4]) = pa0;
    *(f32x4*)(&red[wave][1][lane * 4]) = pa1;
    *(f32x4*)(&red[wave][2][lane * 4]) = pa2;
    *(f32x4*)(&red[wave][3][lane * 4]) = pa3;
  }
  __syncthreads();

  #pragma unroll
  for (int br = 0; br < 4; ++br) {
    float s = red[0][br][tid] + red[1][br][tid] + red[2][br][tid] + red[3][br][tid];
    out[((br * NB + b) * NL + p) * ND + tid] = s * invsum[br];
  }
}

extern "C" void kernel_launch(void* const* d_in, const int* in_sizes, int n_in,
                              void* d_out, int out_size, void* d_ws, size_t ws_size,
                              hipStream_t stream) {
  const float* Hp  = (const float*)d_in[0];
  const float* Hq  = (const float*)d_in[1];
  const float* Wc1 = (const float*)d_in[2];
  const float* Wc2 = (const float*)d_in[3];
  const float* vc  = (const float*)d_in[4];
  const float* Wb  = (const float*)d_in[5];
  const float* Wd  = (const float*)d_in[6];
  const float* vd  = (const float*)d_in[7];
  const float* Wm  = (const float*)d_in[8];
  const float* vm  = (const float*)d_in[9];
  float* ws = (float*)d_ws;
  float* out = (float*)d_out;

  hipLaunchKernelGGL(prep, dim3(128, 7), dim3(256), 0, stream,
                     Hq, Hp, Wc1, Wc2, Wb, Wm, Wd, ws);
  hipLaunchKernelGGL(k2, dim3(2048), dim3(256), 0, stream,
                     Hp, vc, vd, vm, ws, out);
  hipLaunchKernelGGL(k3, dim3(256, 4), dim3(256), 0, stream,
                     Hq, out);
}